// Round 1
// baseline (381.301 us; speedup 1.0000x reference)
//
#include <hip/hip_runtime.h>

#define N_NODES 50000
#define N_EDGES 800000
#define IN_F 256
#define OUT_F 64

// out[i] = bias[i % 64], vectorized: out4[i] = bias4[i & 15]
__global__ __launch_bounds__(256) void gc_init(float* __restrict__ out,
                                               const float* __restrict__ bias) {
    const int total4 = N_NODES * OUT_F / 4;  // 800000 float4
    float4* __restrict__ out4 = (float4*)out;
    const float4* __restrict__ b4 = (const float4*)bias;
    for (int i = blockIdx.x * blockDim.x + threadIdx.x; i < total4;
         i += gridDim.x * blockDim.x) {
        out4[i] = b4[i & 15];
    }
}

// h = x @ W. One wave handles 4 consecutive nodes; lane = output feature.
// W rows read coalesced (256B/wave, L1/L2-resident: W is 64 KB total).
// x rows read as wave-uniform broadcast float4 loads.
__global__ __launch_bounds__(256) void gc_gemm(const float* __restrict__ x,
                                               const float* __restrict__ W,
                                               float* __restrict__ h) {
    const int gw = (blockIdx.x * blockDim.x + threadIdx.x) >> 6;  // global wave id
    const int f = threadIdx.x & 63;
    const int n0 = gw * 4;
    if (n0 >= N_NODES) return;  // 50000 % 4 == 0, so no partial groups
    const float* __restrict__ xr = x + (size_t)n0 * IN_F;
    float a0 = 0.f, a1 = 0.f, a2 = 0.f, a3 = 0.f;
#pragma unroll 4
    for (int k = 0; k < IN_F; k += 4) {
        const float wk0 = W[(k + 0) * OUT_F + f];
        const float wk1 = W[(k + 1) * OUT_F + f];
        const float wk2 = W[(k + 2) * OUT_F + f];
        const float wk3 = W[(k + 3) * OUT_F + f];
        const float4 x0 = *(const float4*)(xr + 0 * IN_F + k);
        const float4 x1 = *(const float4*)(xr + 1 * IN_F + k);
        const float4 x2 = *(const float4*)(xr + 2 * IN_F + k);
        const float4 x3 = *(const float4*)(xr + 3 * IN_F + k);
        a0 += x0.x * wk0 + x0.y * wk1 + x0.z * wk2 + x0.w * wk3;
        a1 += x1.x * wk0 + x1.y * wk1 + x1.z * wk2 + x1.w * wk3;
        a2 += x2.x * wk0 + x2.y * wk1 + x2.z * wk2 + x2.w * wk3;
        a3 += x3.x * wk0 + x3.y * wk1 + x3.z * wk2 + x3.w * wk3;
    }
    h[(size_t)(n0 + 0) * OUT_F + f] = a0;
    h[(size_t)(n0 + 1) * OUT_F + f] = a1;
    h[(size_t)(n0 + 2) * OUT_F + f] = a2;
    h[(size_t)(n0 + 3) * OUT_F + f] = a3;
}

// One wave per edge (grid-stride): lane f does
//   atomicAdd(&out[dst*64+f], ew * h[src*64+f])
// Gather is a coalesced 256B read (h is 12.8 MB -> L2/L3 resident).
__global__ __launch_bounds__(256) void gc_scatter(const float* __restrict__ h,
                                                  const float* __restrict__ ew,
                                                  const int* __restrict__ src,
                                                  const int* __restrict__ dst,
                                                  float* __restrict__ out) {
    const int gw = (blockIdx.x * blockDim.x + threadIdx.x) >> 6;
    const int f = threadIdx.x & 63;
    const int nwaves = (gridDim.x * blockDim.x) >> 6;
    for (int e = gw; e < N_EDGES; e += nwaves) {
        const int s = src[e];
        const int d = dst[e];
        const float w = ew[e];
        const float v = h[(size_t)s * OUT_F + f] * w;
        atomicAdd(&out[(size_t)d * OUT_F + f], v);
    }
}

extern "C" void kernel_launch(void* const* d_in, const int* in_sizes, int n_in,
                              void* d_out, int out_size, void* d_ws, size_t ws_size,
                              hipStream_t stream) {
    const float* x    = (const float*)d_in[0];
    const float* W    = (const float*)d_in[1];
    const float* bias = (const float*)d_in[2];
    const float* ew   = (const float*)d_in[3];
    const int* src    = (const int*)d_in[4];
    const int* dst    = (const int*)d_in[5];
    float* out = (float*)d_out;
    float* h = (float*)d_ws;  // 50000*64*4 = 12.8 MB scratch, fully overwritten

    // 1) out = bias (broadcast). Must run before scatter (same stream => ordered).
    gc_init<<<1024, 256, 0, stream>>>(out, bias);

    // 2) h = x @ W. 12500 waves of 4 nodes each -> 3125 blocks of 256.
    gc_gemm<<<(N_NODES / 4 * 64) / 256, 256, 0, stream>>>(x, W, h);

    // 3) scatter-add over edges.
    gc_scatter<<<8192, 256, 0, stream>>>(h, ew, src, dst, out);
}

// Round 2
// 348.912 us; speedup vs baseline: 1.0928x; 1.0928x over previous
//
#include <hip/hip_runtime.h>

#define N_NODES 50000
#define N_EDGES 800000
#define IN_F 256
#define OUT_F 64

#define TNODE 32  // nodes per gemm block (8 per wave x 4 waves)

// ---------------- GEMM: h = x @ W ----------------
// Block 256 = 4 waves. Each block stages 32 x-rows (32 KB) into LDS with
// coalesced float4 loads. Each wave computes 8 nodes; lane = out feature.
// Per k4-step: 4 coalesced W loads (256B, L1-resident) reused across 8 nodes,
// 8 broadcast ds_read_b128 for x, 32 FMAs.
__global__ __launch_bounds__(256) void gc_gemm(const float* __restrict__ x,
                                               const float* __restrict__ W,
                                               float* __restrict__ h) {
    __shared__ float xs[TNODE * IN_F];  // 32 KB
    const int t = threadIdx.x;
    const int nbase = blockIdx.x * TNODE;
    const int nvalid = min(TNODE, N_NODES - nbase);

    // stage x tile: nvalid*64 float4, 256 threads
    {
        const float4* __restrict__ xg = (const float4*)(x + (size_t)nbase * IN_F);
        float4* __restrict__ xs4 = (float4*)xs;
        const int lim4 = nvalid * (IN_F / 4);
#pragma unroll
        for (int i = 0; i < TNODE * IN_F / 4 / 256; ++i) {
            const int idx = t + i * 256;
            if (idx < lim4) xs4[idx] = xg[idx];
        }
    }
    __syncthreads();

    const int wave = t >> 6;
    const int f = t & 63;
    const int n0 = wave * 8;  // within tile

    float acc[8];
#pragma unroll
    for (int j = 0; j < 8; ++j) acc[j] = 0.f;

#pragma unroll 2
    for (int k = 0; k < IN_F; k += 4) {
        const float w0 = W[(k + 0) * OUT_F + f];
        const float w1 = W[(k + 1) * OUT_F + f];
        const float w2 = W[(k + 2) * OUT_F + f];
        const float w3 = W[(k + 3) * OUT_F + f];
#pragma unroll
        for (int j = 0; j < 8; ++j) {
            const float4 xv = *(const float4*)&xs[(n0 + j) * IN_F + k];
            acc[j] += xv.x * w0 + xv.y * w1 + xv.z * w2 + xv.w * w3;
        }
    }

#pragma unroll
    for (int j = 0; j < 8; ++j) {
        const int n = nbase + n0 + j;
        if (n < N_NODES) h[(size_t)n * OUT_F + f] = acc[j];
    }
}

// ---------------- CSR build ----------------
__global__ __launch_bounds__(256) void gc_hist(const int* __restrict__ dst,
                                               int* __restrict__ cnt) {
    const int i = blockIdx.x * blockDim.x + threadIdx.x;
    if (i < N_EDGES) atomicAdd(&cnt[dst[i]], 1);
}

#define SCAN_T 1024
#define SCAN_CH 49  // 1024*49 = 50176 >= 50000
__global__ __launch_bounds__(1024) void gc_scan(const int* __restrict__ cnt,
                                                int* __restrict__ offs,
                                                int* __restrict__ cursor) {
    __shared__ int sd[SCAN_T];
    const int t = threadIdx.x;
    const int base = t * SCAN_CH;
    int loc[SCAN_CH];
    int s = 0;
#pragma unroll
    for (int i = 0; i < SCAN_CH; ++i) {
        const int idx = base + i;
        const int v = (idx < N_NODES) ? cnt[idx] : 0;
        loc[i] = v;
        s += v;
    }
    sd[t] = s;
    __syncthreads();
    for (int d = 1; d < SCAN_T; d <<= 1) {
        const int v = (t >= d) ? sd[t - d] : 0;
        __syncthreads();
        sd[t] += v;
        __syncthreads();
    }
    int run = sd[t] - s;  // exclusive prefix of this chunk
#pragma unroll
    for (int i = 0; i < SCAN_CH; ++i) {
        const int idx = base + i;
        if (idx < N_NODES) {
            offs[idx] = run;
            cursor[idx] = run;
            run += loc[i];
        }
    }
    if (t == SCAN_T - 1) offs[N_NODES] = run;
}

__global__ __launch_bounds__(256) void gc_fill(const int* __restrict__ src,
                                               const int* __restrict__ dst,
                                               const float* __restrict__ ew,
                                               int* __restrict__ cursor,
                                               int2* __restrict__ sorted) {
    const int i = blockIdx.x * blockDim.x + threadIdx.x;
    if (i < N_EDGES) {
        const int d = dst[i];
        const int pos = atomicAdd(&cursor[d], 1);
        sorted[pos] = make_int2(src[i], __float_as_int(ew[i]));
    }
}

// ---------------- gather: out[d] = bias + sum w*h[src] ----------------
// One wave per dst node; lane = feature. Segment header loads are
// wave-uniform (scalar path); h gathers are coalesced 256B reads.
__global__ __launch_bounds__(256) void gc_gather(const float* __restrict__ h,
                                                 const int2* __restrict__ sorted,
                                                 const int* __restrict__ offs,
                                                 const float* __restrict__ bias,
                                                 float* __restrict__ out) {
    const int gw = (blockIdx.x * blockDim.x + threadIdx.x) >> 6;
    const int f = threadIdx.x & 63;
    if (gw >= N_NODES) return;
    const int beg = offs[gw];
    const int end = offs[gw + 1];
    float acc = bias[f];
    int i = beg;
    for (; i + 2 <= end; i += 2) {
        const int2 e0 = sorted[i];
        const int2 e1 = sorted[i + 1];
        acc += __int_as_float(e0.y) * h[(size_t)e0.x * OUT_F + f];
        acc += __int_as_float(e1.y) * h[(size_t)e1.x * OUT_F + f];
    }
    if (i < end) {
        const int2 e0 = sorted[i];
        acc += __int_as_float(e0.y) * h[(size_t)e0.x * OUT_F + f];
    }
    out[(size_t)gw * OUT_F + f] = acc;
}

extern "C" void kernel_launch(void* const* d_in, const int* in_sizes, int n_in,
                              void* d_out, int out_size, void* d_ws, size_t ws_size,
                              hipStream_t stream) {
    const float* x    = (const float*)d_in[0];
    const float* W    = (const float*)d_in[1];
    const float* bias = (const float*)d_in[2];
    const float* ew   = (const float*)d_in[3];
    const int* src    = (const int*)d_in[4];
    const int* dst    = (const int*)d_in[5];
    float* out = (float*)d_out;

    // workspace layout (all 16B-aligned)
    char* ws = (char*)d_ws;
    float* h      = (float*)ws;                       // 12,800,000 B
    int*   cnt    = (int*)(ws + 12800000);            // 200,016 B (50001 ints)
    int*   offs   = (int*)(ws + 13000016);            // 200,016 B (50001 ints)
    int*   cursor = (int*)(ws + 13200032);            // 200,000 B
    int2*  sorted = (int2*)(ws + 13400032);           // 6,400,000 B  (end 19.8 MB)

    hipMemsetAsync(cnt, 0, (size_t)N_NODES * sizeof(int), stream);

    gc_hist<<<(N_EDGES + 255) / 256, 256, 0, stream>>>(dst, cnt);
    gc_scan<<<1, SCAN_T, 0, stream>>>(cnt, offs, cursor);
    gc_fill<<<(N_EDGES + 255) / 256, 256, 0, stream>>>(src, dst, ew, cursor, sorted);

    gc_gemm<<<(N_NODES + TNODE - 1) / TNODE, 256, 0, stream>>>(x, W, h);

    gc_gather<<<(N_NODES * 64 + 255) / 256, 256, 0, stream>>>(h, sorted, offs, bias, out);
}

// Round 3
// 265.183 us; speedup vs baseline: 1.4379x; 1.3157x over previous
//
#include <hip/hip_runtime.h>

#define N_NODES 50000
#define N_EDGES 800000
#define IN_F 256
#define OUT_F 64

#define TNODE 32   // nodes per gemm block (8 per wave x 4 waves)
#define NB 196     // scan blocks: 196*256 = 50176 >= 50000

// ---------------- GEMM: h = x @ W ----------------
__global__ __launch_bounds__(256) void gc_gemm(const float* __restrict__ x,
                                               const float* __restrict__ W,
                                               float* __restrict__ h) {
    __shared__ float xs[TNODE * IN_F];  // 32 KB
    const int t = threadIdx.x;
    const int nbase = blockIdx.x * TNODE;
    const int nvalid = min(TNODE, N_NODES - nbase);

    {
        const float4* __restrict__ xg = (const float4*)(x + (size_t)nbase * IN_F);
        float4* __restrict__ xs4 = (float4*)xs;
        const int lim4 = nvalid * (IN_F / 4);
#pragma unroll
        for (int i = 0; i < TNODE * IN_F / 4 / 256; ++i) {
            const int idx = t + i * 256;
            if (idx < lim4) xs4[idx] = xg[idx];
        }
    }
    __syncthreads();

    const int wave = t >> 6;
    const int f = t & 63;
    const int n0 = wave * 8;

    float acc[8];
#pragma unroll
    for (int j = 0; j < 8; ++j) acc[j] = 0.f;

#pragma unroll 2
    for (int k = 0; k < IN_F; k += 4) {
        const float w0 = W[(k + 0) * OUT_F + f];
        const float w1 = W[(k + 1) * OUT_F + f];
        const float w2 = W[(k + 2) * OUT_F + f];
        const float w3 = W[(k + 3) * OUT_F + f];
#pragma unroll
        for (int j = 0; j < 8; ++j) {
            const float4 xv = *(const float4*)&xs[(n0 + j) * IN_F + k];
            acc[j] += xv.x * w0 + xv.y * w1 + xv.z * w2 + xv.w * w3;
        }
    }

#pragma unroll
    for (int j = 0; j < 8; ++j) {
        const int n = nbase + n0 + j;
        if (n < N_NODES) h[(size_t)n * OUT_F + f] = acc[j];
    }
}

// ---------------- CSR build ----------------
__global__ __launch_bounds__(256) void gc_hist(const int* __restrict__ dst,
                                               int* __restrict__ cnt) {
    const int i = blockIdx.x * blockDim.x + threadIdx.x;
    if (i < N_EDGES) atomicAdd(&cnt[dst[i]], 1);
}

// A: per-block sum of 256 counts -> bsum[block]
__global__ __launch_bounds__(256) void gc_scan_reduce(const int* __restrict__ cnt,
                                                      int* __restrict__ bsum) {
    __shared__ int sd[4];
    const int i = blockIdx.x * 256 + threadIdx.x;
    int v = (i < N_NODES) ? cnt[i] : 0;
#pragma unroll
    for (int d = 32; d > 0; d >>= 1) v += __shfl_down(v, d, 64);
    if ((threadIdx.x & 63) == 0) sd[threadIdx.x >> 6] = v;
    __syncthreads();
    if (threadIdx.x == 0) bsum[blockIdx.x] = sd[0] + sd[1] + sd[2] + sd[3];
}

// B: exclusive scan of NB block sums -> bpre; also writes offs[N_NODES]=total
__global__ __launch_bounds__(256) void gc_scan_tops(const int* __restrict__ bsum,
                                                    int* __restrict__ bpre,
                                                    int* __restrict__ offs) {
    __shared__ int sd[256];
    const int t = threadIdx.x;
    const int v = (t < NB) ? bsum[t] : 0;
    sd[t] = v;
    __syncthreads();
#pragma unroll
    for (int d = 1; d < 256; d <<= 1) {
        const int u = (t >= d) ? sd[t - d] : 0;
        __syncthreads();
        sd[t] += u;
        __syncthreads();
    }
    if (t < NB) bpre[t] = sd[t] - v;  // exclusive
    if (t == NB - 1) offs[N_NODES] = sd[t];
}

// C: block-local exclusive scan + base -> offs, cursor
__global__ __launch_bounds__(256) void gc_scan_down(const int* __restrict__ cnt,
                                                    const int* __restrict__ bpre,
                                                    int* __restrict__ offs,
                                                    int* __restrict__ cursor) {
    __shared__ int sd[256];
    const int t = threadIdx.x;
    const int i = blockIdx.x * 256 + t;
    const int v = (i < N_NODES) ? cnt[i] : 0;
    sd[t] = v;
    __syncthreads();
#pragma unroll
    for (int d = 1; d < 256; d <<= 1) {
        const int u = (t >= d) ? sd[t - d] : 0;
        __syncthreads();
        sd[t] += u;
        __syncthreads();
    }
    if (i < N_NODES) {
        const int off = bpre[blockIdx.x] + sd[t] - v;
        offs[i] = off;
        cursor[i] = off;
    }
}

__global__ __launch_bounds__(256) void gc_fill(const int* __restrict__ src,
                                               const int* __restrict__ dst,
                                               const float* __restrict__ ew,
                                               int* __restrict__ cursor,
                                               int2* __restrict__ sorted) {
    const int i = blockIdx.x * blockDim.x + threadIdx.x;
    if (i < N_EDGES) {
        const int d = dst[i];
        const int pos = atomicAdd(&cursor[d], 1);
        sorted[pos] = make_int2(src[i], __float_as_int(ew[i]));
    }
}

// ---------------- gather: out[d] = bias + sum w*h[src] ----------------
__global__ __launch_bounds__(256) void gc_gather(const float* __restrict__ h,
                                                 const int2* __restrict__ sorted,
                                                 const int* __restrict__ offs,
                                                 const float* __restrict__ bias,
                                                 float* __restrict__ out) {
    const int gw = (blockIdx.x * blockDim.x + threadIdx.x) >> 6;
    const int f = threadIdx.x & 63;
    if (gw >= N_NODES) return;
    const int beg = offs[gw];
    const int end = offs[gw + 1];
    float acc = bias[f];
    int i = beg;
    // unroll-4: issue 4 independent edge loads + 4 independent h gathers
    for (; i + 4 <= end; i += 4) {
        const int2 e0 = sorted[i + 0];
        const int2 e1 = sorted[i + 1];
        const int2 e2 = sorted[i + 2];
        const int2 e3 = sorted[i + 3];
        const float h0 = h[(size_t)e0.x * OUT_F + f];
        const float h1 = h[(size_t)e1.x * OUT_F + f];
        const float h2 = h[(size_t)e2.x * OUT_F + f];
        const float h3 = h[(size_t)e3.x * OUT_F + f];
        acc += __int_as_float(e0.y) * h0;
        acc += __int_as_float(e1.y) * h1;
        acc += __int_as_float(e2.y) * h2;
        acc += __int_as_float(e3.y) * h3;
    }
    for (; i < end; ++i) {
        const int2 e0 = sorted[i];
        acc += __int_as_float(e0.y) * h[(size_t)e0.x * OUT_F + f];
    }
    out[(size_t)gw * OUT_F + f] = acc;
}

extern "C" void kernel_launch(void* const* d_in, const int* in_sizes, int n_in,
                              void* d_out, int out_size, void* d_ws, size_t ws_size,
                              hipStream_t stream) {
    const float* x    = (const float*)d_in[0];
    const float* W    = (const float*)d_in[1];
    const float* bias = (const float*)d_in[2];
    const float* ew   = (const float*)d_in[3];
    const int* src    = (const int*)d_in[4];
    const int* dst    = (const int*)d_in[5];
    float* out = (float*)d_out;

    // workspace layout (16B-aligned)
    char* ws = (char*)d_ws;
    float* h      = (float*)ws;                       // 12,800,000 B
    int*   cnt    = (int*)(ws + 12800000);            // 200,000 B
    int*   offs   = (int*)(ws + 13000000);            // 200,004 B (50001)
    int*   cursor = (int*)(ws + 13200016);            // 200,000 B
    int*   bsum   = (int*)(ws + 13400016);            // 784 B
    int*   bpre   = (int*)(ws + 13400800);            // 784 B
    int2*  sorted = (int2*)(ws + 13401600);           // 6,400,000 B (end ~19.8 MB)

    hipMemsetAsync(cnt, 0, (size_t)N_NODES * sizeof(int), stream);

    gc_hist<<<(N_EDGES + 255) / 256, 256, 0, stream>>>(dst, cnt);
    gc_scan_reduce<<<NB, 256, 0, stream>>>(cnt, bsum);
    gc_scan_tops<<<1, 256, 0, stream>>>(bsum, bpre, offs);
    gc_scan_down<<<NB, 256, 0, stream>>>(cnt, bpre, offs, cursor);
    gc_fill<<<(N_EDGES + 255) / 256, 256, 0, stream>>>(src, dst, ew, cursor, sorted);

    gc_gemm<<<(N_NODES + TNODE - 1) / TNODE, 256, 0, stream>>>(x, W, h);

    gc_gather<<<(N_NODES * 64 + 255) / 256, 256, 0, stream>>>(h, sorted, offs, bias, out);
}

// Round 4
// 254.893 us; speedup vs baseline: 1.4959x; 1.0404x over previous
//
#include <hip/hip_runtime.h>

#define N_NODES 50000
#define N_EDGES 800000
#define IN_F 256
#define OUT_F 64

#define NB 196     // scan blocks: 196*256 = 50176 >= 50000

// ---------------- GEMM: h = x @ W ----------------
// Block = 512 thr = 8 waves; tile = 64 nodes x 64 features.
// lane = node (per-lane-distinct LDS reads, 256B useful per ds_read_b128),
// wave = 8-feature slice, W served via wave-uniform scalar loads (SGPR path).
// x tile staged in LDS in two K-phases of 128 (64 x 132 floats = 33 KB).
__global__ __launch_bounds__(512) void gc_gemm(const float* __restrict__ x,
                                               const float* __restrict__ W,
                                               float* __restrict__ h) {
    __shared__ float xs[64 * 132];  // pad 132: conflict-free column b128 reads
    const int t = threadIdx.x;
    const int lane = t & 63;
    const int nbase = blockIdx.x * 64;
    const int nvalid = min(64, N_NODES - nbase);

    // force wave-uniform feature base -> scalar (s_load) W accesses
    const int f0 = __builtin_amdgcn_readfirstlane(t >> 6) * 8;
    const float* __restrict__ Wf = W + f0;

    float acc[8];
#pragma unroll
    for (int j = 0; j < 8; ++j) acc[j] = 0.f;

    const float4* __restrict__ xg = (const float4*)x;  // row stride 64 float4

#pragma unroll
    for (int phase = 0; phase < 2; ++phase) {
        // stage 64 nodes x 128 k (nvalid*32 float4s) coalesced
        __syncthreads();  // phase 1: ensure phase-0 reads done before overwrite
        {
            const int lim = nvalid * 32;
#pragma unroll
            for (int i = 0; i < 4; ++i) {
                const int idx = t + i * 512;
                if (idx < lim) {
                    const int n = idx >> 5;
                    const int c4 = idx & 31;
                    *(float4*)&xs[n * 132 + c4 * 4] =
                        xg[(size_t)(nbase + n) * 64 + phase * 32 + c4];
                }
            }
        }
        __syncthreads();

        const int kbase = phase * 128;
        for (int k4 = 0; k4 < 32; ++k4) {
            const float4 xv = *(const float4*)&xs[lane * 132 + k4 * 4];
            const int k = kbase + k4 * 4;
#pragma unroll
            for (int j = 0; j < 8; ++j) {
                acc[j] += xv.x * Wf[(k + 0) * OUT_F + j]
                        + xv.y * Wf[(k + 1) * OUT_F + j]
                        + xv.z * Wf[(k + 2) * OUT_F + j]
                        + xv.w * Wf[(k + 3) * OUT_F + j];
            }
        }
    }

    if (lane < nvalid) {
        const size_t base = (size_t)(nbase + lane) * OUT_F + f0;
        *(float4*)&h[base]     = make_float4(acc[0], acc[1], acc[2], acc[3]);
        *(float4*)&h[base + 4] = make_float4(acc[4], acc[5], acc[6], acc[7]);
    }
}

// ---------------- CSR build ----------------
__global__ __launch_bounds__(256) void gc_hist(const int* __restrict__ dst,
                                               int* __restrict__ cnt) {
    const int i = blockIdx.x * blockDim.x + threadIdx.x;
    if (i < N_EDGES) atomicAdd(&cnt[dst[i]], 1);
}

// A: per-block sum of 256 counts -> bsum[block]
__global__ __launch_bounds__(256) void gc_scan_reduce(const int* __restrict__ cnt,
                                                      int* __restrict__ bsum) {
    __shared__ int sd[4];
    const int i = blockIdx.x * 256 + threadIdx.x;
    int v = (i < N_NODES) ? cnt[i] : 0;
#pragma unroll
    for (int d = 32; d > 0; d >>= 1) v += __shfl_down(v, d, 64);
    if ((threadIdx.x & 63) == 0) sd[threadIdx.x >> 6] = v;
    __syncthreads();
    if (threadIdx.x == 0) bsum[blockIdx.x] = sd[0] + sd[1] + sd[2] + sd[3];
}

// B: exclusive scan of NB block sums -> bpre; also writes offs[N_NODES]=total
__global__ __launch_bounds__(256) void gc_scan_tops(const int* __restrict__ bsum,
                                                    int* __restrict__ bpre,
                                                    int* __restrict__ offs) {
    __shared__ int sd[256];
    const int t = threadIdx.x;
    const int v = (t < NB) ? bsum[t] : 0;
    sd[t] = v;
    __syncthreads();
#pragma unroll
    for (int d = 1; d < 256; d <<= 1) {
        const int u = (t >= d) ? sd[t - d] : 0;
        __syncthreads();
        sd[t] += u;
        __syncthreads();
    }
    if (t < NB) bpre[t] = sd[t] - v;  // exclusive
    if (t == NB - 1) offs[N_NODES] = sd[t];
}

// C: block-local exclusive scan + base -> offs, cursor
__global__ __launch_bounds__(256) void gc_scan_down(const int* __restrict__ cnt,
                                                    const int* __restrict__ bpre,
                                                    int* __restrict__ offs,
                                                    int* __restrict__ cursor) {
    __shared__ int sd[256];
    const int t = threadIdx.x;
    const int i = blockIdx.x * 256 + t;
    const int v = (i < N_NODES) ? cnt[i] : 0;
    sd[t] = v;
    __syncthreads();
#pragma unroll
    for (int d = 1; d < 256; d <<= 1) {
        const int u = (t >= d) ? sd[t - d] : 0;
        __syncthreads();
        sd[t] += u;
        __syncthreads();
    }
    if (i < N_NODES) {
        const int off = bpre[blockIdx.x] + sd[t] - v;
        offs[i] = off;
        cursor[i] = off;
    }
}

__global__ __launch_bounds__(256) void gc_fill(const int* __restrict__ src,
                                               const int* __restrict__ dst,
                                               const float* __restrict__ ew,
                                               int* __restrict__ cursor,
                                               int2* __restrict__ sorted) {
    const int i = blockIdx.x * blockDim.x + threadIdx.x;
    if (i < N_EDGES) {
        const int d = dst[i];
        const int pos = atomicAdd(&cursor[d], 1);
        sorted[pos] = make_int2(src[i], __float_as_int(ew[i]));
    }
}

// ---------------- gather: out[d] = bias + sum w*h[src] ----------------
__global__ __launch_bounds__(256) void gc_gather(const float* __restrict__ h,
                                                 const int2* __restrict__ sorted,
                                                 const int* __restrict__ offs,
                                                 const float* __restrict__ bias,
                                                 float* __restrict__ out) {
    const int gw = (blockIdx.x * blockDim.x + threadIdx.x) >> 6;
    const int f = threadIdx.x & 63;
    if (gw >= N_NODES) return;
    const int beg = offs[gw];
    const int end = offs[gw + 1];
    float acc = bias[f];
    int i = beg;
    for (; i + 4 <= end; i += 4) {
        const int2 e0 = sorted[i + 0];
        const int2 e1 = sorted[i + 1];
        const int2 e2 = sorted[i + 2];
        const int2 e3 = sorted[i + 3];
        const float h0 = h[(size_t)e0.x * OUT_F + f];
        const float h1 = h[(size_t)e1.x * OUT_F + f];
        const float h2 = h[(size_t)e2.x * OUT_F + f];
        const float h3 = h[(size_t)e3.x * OUT_F + f];
        acc += __int_as_float(e0.y) * h0;
        acc += __int_as_float(e1.y) * h1;
        acc += __int_as_float(e2.y) * h2;
        acc += __int_as_float(e3.y) * h3;
    }
    for (; i < end; ++i) {
        const int2 e0 = sorted[i];
        acc += __int_as_float(e0.y) * h[(size_t)e0.x * OUT_F + f];
    }
    out[(size_t)gw * OUT_F + f] = acc;
}

extern "C" void kernel_launch(void* const* d_in, const int* in_sizes, int n_in,
                              void* d_out, int out_size, void* d_ws, size_t ws_size,
                              hipStream_t stream) {
    const float* x    = (const float*)d_in[0];
    const float* W    = (const float*)d_in[1];
    const float* bias = (const float*)d_in[2];
    const float* ew   = (const float*)d_in[3];
    const int* src    = (const int*)d_in[4];
    const int* dst    = (const int*)d_in[5];
    float* out = (float*)d_out;

    // workspace layout (16B-aligned)
    char* ws = (char*)d_ws;
    float* h      = (float*)ws;                       // 12,800,000 B
    int*   cnt    = (int*)(ws + 12800000);            // 200,000 B
    int*   offs   = (int*)(ws + 13000000);            // 200,004 B (50001)
    int*   cursor = (int*)(ws + 13200016);            // 200,000 B
    int*   bsum   = (int*)(ws + 13400016);            // 784 B
    int*   bpre   = (int*)(ws + 13400800);            // 784 B
    int2*  sorted = (int2*)(ws + 13401600);           // 6,400,000 B (end ~19.8 MB)

    hipMemsetAsync(cnt, 0, (size_t)N_NODES * sizeof(int), stream);

    gc_hist<<<(N_EDGES + 255) / 256, 256, 0, stream>>>(dst, cnt);
    gc_scan_reduce<<<NB, 256, 0, stream>>>(cnt, bsum);
    gc_scan_tops<<<1, 256, 0, stream>>>(bsum, bpre, offs);
    gc_scan_down<<<NB, 256, 0, stream>>>(cnt, bpre, offs, cursor);
    gc_fill<<<(N_EDGES + 255) / 256, 256, 0, stream>>>(src, dst, ew, cursor, sorted);

    gc_gemm<<<(N_NODES + 63) / 64, 512, 0, stream>>>(x, W, h);

    gc_gather<<<(N_NODES * 64 + 255) / 256, 256, 0, stream>>>(h, sorted, offs, bias, out);
}